// Round 2
// baseline (1194.749 us; speedup 1.0000x reference)
//
#include <hip/hip_runtime.h>
#include <stdint.h>

typedef __bf16 bf16x8 __attribute__((ext_vector_type(8)));
typedef float f32x4 __attribute__((ext_vector_type(4)));

__device__ __forceinline__ unsigned short f2bf(float f) {
    union { float f; uint32_t i; } v;
    v.f = f;
    uint32_t x = v.i;
    return (unsigned short)((x + 0x7FFFu + ((x >> 16) & 1u)) >> 16);  // RNE
}
__device__ __forceinline__ float bf2f(unsigned short u) {
    union { uint32_t i; float f; } v;
    v.i = ((uint32_t)u) << 16;
    return v.f;
}

// ---------------------------------------------------------------------------
// Flat f32 -> bf16 convert (weights). n % 1024 == 0.
// ---------------------------------------------------------------------------
__global__ __launch_bounds__(256) void cvt_flat(
    const float* __restrict__ in, unsigned short* __restrict__ out, int n)
{
    const int i = (blockIdx.x * 256 + threadIdx.x) * 4;
    if (i < n) {
        const float4 v = *(const float4*)(in + i);
        out[i + 0] = f2bf(v.x);
        out[i + 1] = f2bf(v.y);
        out[i + 2] = f2bf(v.z);
        out[i + 3] = f2bf(v.w);
    }
}

// ---------------------------------------------------------------------------
// f32 [R][C] -> bf16 [C][R], batched over blockIdx.z. R,C multiples of 32.
// ---------------------------------------------------------------------------
__global__ __launch_bounds__(256) void cvt_transpose(
    const float* __restrict__ in, unsigned short* __restrict__ out,
    int R, int C)
{
    __shared__ unsigned short tile[32][33];
    const size_t bo = (size_t)blockIdx.z * R * C;
    const int c0 = blockIdx.x * 32, r0 = blockIdx.y * 32;
    const int tx = threadIdx.x & 31, ty = threadIdx.x >> 5;  // ty 0..7
#pragma unroll
    for (int i = 0; i < 4; ++i)
        tile[ty + i * 8][tx] = f2bf(in[bo + (size_t)(r0 + ty + i * 8) * C + (c0 + tx)]);
    __syncthreads();
#pragma unroll
    for (int i = 0; i < 4; ++i)
        out[bo + (size_t)(c0 + ty + i * 8) * R + (r0 + tx)] = tile[tx][ty + i * 8];
}

// ---------------------------------------------------------------------------
// bf16 [R][C] -> bf16 [C][R], batched (msg re-layout).
// ---------------------------------------------------------------------------
__global__ __launch_bounds__(256) void transpose_bf16(
    const unsigned short* __restrict__ in, unsigned short* __restrict__ out,
    int R, int C)
{
    __shared__ unsigned short tile[32][33];
    const size_t bo = (size_t)blockIdx.z * R * C;
    const int c0 = blockIdx.x * 32, r0 = blockIdx.y * 32;
    const int tx = threadIdx.x & 31, ty = threadIdx.x >> 5;
#pragma unroll
    for (int i = 0; i < 4; ++i)
        tile[ty + i * 8][tx] = in[bo + (size_t)(r0 + ty + i * 8) * C + (c0 + tx)];
    __syncthreads();
#pragma unroll
    for (int i = 0; i < 4; ++i)
        out[bo + (size_t)(c0 + ty + i * 8) * R + (r0 + tx)] = tile[tx][ty + i * 8];
}

// ---------------------------------------------------------------------------
// C[m][n'] = sum_k A[m][k] * BT[n'][k]   (both operands k-contiguous, bf16)
// 128x128 tile, BK=32, 4 waves, each wave 64x64 via 4x4 mfma_f32_16x16x32_bf16.
// A may be channel-concat (A for k<K1, A2 for k>=K1; same lda/strideA).
// Epilogue: optional f32 per-row bias (bias_m), per-col bias (bias_n),
// per-col BN(eval,eps=1e-3)+ReLU; output bf16 (C) or f32 (Cf) if Cf!=null.
// M%128==0, N'%128==0, K%32==0 for every call here.
// ---------------------------------------------------------------------------
__global__ __launch_bounds__(256) void gemm_bt(
    const unsigned short* __restrict__ A,
    const unsigned short* __restrict__ A2, int K1,
    const unsigned short* __restrict__ BT,
    unsigned short* __restrict__ C, float* __restrict__ Cf,
    int Kdim, int lda, int ldb, int ldc,
    long long strideA, long long strideB, long long strideC,
    const float* __restrict__ bias_m,
    const float* __restrict__ bias_n,
    const float* __restrict__ bn_g,
    const float* __restrict__ bn_b,
    const float* __restrict__ bn_mu,
    const float* __restrict__ bn_var)
{
    constexpr int SA = 40;  // 32 + 8 pad: frag reads land 2-way max on banks (free)
    __shared__ __align__(16) unsigned short As[128 * SA];
    __shared__ __align__(16) unsigned short Bs[128 * SA];

    const int m0 = blockIdx.y * 128, n0 = blockIdx.x * 128;
    const unsigned short* Ab  = A + (size_t)blockIdx.z * strideA;
    const unsigned short* A2b = A2 ? A2 + (size_t)blockIdx.z * strideA
                                   : (const unsigned short*)0;
    const unsigned short* Bb = BT + (size_t)blockIdx.z * strideB;

    const int t = threadIdx.x;
    const int lane = t & 63, wid = t >> 6;
    const int wm = wid >> 1, wn = wid & 1;
    const int r16 = lane & 15, quad = lane >> 4;
    const int arow = t >> 2, achunk = (t & 3) * 8;

    f32x4 acc[4][4];
    const f32x4 zf = {0.f, 0.f, 0.f, 0.f};
#pragma unroll
    for (int i = 0; i < 4; ++i)
#pragma unroll
        for (int j = 0; j < 4; ++j) acc[i][j] = zf;

    for (int kt = 0; kt < Kdim; kt += 32) {
        const unsigned short* Asrc;
        int kk;
        if (kt < K1) { Asrc = Ab; kk = kt; } else { Asrc = A2b; kk = kt - K1; }
#pragma unroll
        for (int j = 0; j < 2; ++j) {
            const int row = j * 64 + arow;
            *(int4*)(&As[row * SA + achunk]) =
                *(const int4*)(&Asrc[(size_t)(m0 + row) * lda + (kk + achunk)]);
            *(int4*)(&Bs[row * SA + achunk]) =
                *(const int4*)(&Bb[(size_t)(n0 + row) * ldb + (kt + achunk)]);
        }
        __syncthreads();
        bf16x8 af[4], bfb[4];
#pragma unroll
        for (int i = 0; i < 4; ++i) {
            af[i]  = *(const bf16x8*)(&As[(wm * 64 + i * 16 + r16) * SA + quad * 8]);
            bfb[i] = *(const bf16x8*)(&Bs[(wn * 64 + i * 16 + r16) * SA + quad * 8]);
        }
#pragma unroll
        for (int mi = 0; mi < 4; ++mi)
#pragma unroll
            for (int ni = 0; ni < 4; ++ni)
                acc[mi][ni] = __builtin_amdgcn_mfma_f32_16x16x32_bf16(
                    af[mi], bfb[ni], acc[mi][ni], 0, 0, 0);
        __syncthreads();
    }

    unsigned short* Cb = C ? C + (size_t)blockIdx.z * strideC : (unsigned short*)0;
    float* Cfb = Cf ? Cf + (size_t)blockIdx.z * strideC : (float*)0;
    const bool has_bn = (bn_g != 0);
#pragma unroll
    for (int ni = 0; ni < 4; ++ni) {
        const int gn = n0 + wn * 64 + ni * 16 + r16;
        const float addn = bias_n ? bias_n[gn] : 0.f;
        float g = 1.f, bb = 0.f, mu = 0.f, rstd = 1.f;
        if (has_bn) {
            g = bn_g[gn]; bb = bn_b[gn]; mu = bn_mu[gn];
            rstd = rsqrtf(bn_var[gn] + 1e-3f);
        }
#pragma unroll
        for (int mi = 0; mi < 4; ++mi) {
            const int gm0 = m0 + wm * 64 + mi * 16 + quad * 4;
#pragma unroll
            for (int r = 0; r < 4; ++r) {
                float v = acc[mi][ni][r] + addn;
                if (bias_m) v += bias_m[gm0 + r];
                if (has_bn) { v = g * (v - mu) * rstd + bb; v = fmaxf(v, 0.f); }
                const size_t idx = (size_t)(gm0 + r) * ldc + gn;
                if (Cfb) Cfb[idx] = v;
                else     Cb[idx]  = f2bf(v);
            }
        }
    }
}

// ---------------------------------------------------------------------------
// Linformer attention, K=128, DH=64, H=16. One block = 256 n's x one (b,h).
// q, kp, msg all channel-major bf16: q[b][dh*16+h][n], kp[b][dh*16+h][kk].
// v == k (share_kv + shared projection), so PV reuses Ks.
// Scores ~N(0,1.8) -> single-pass softmax is safe in fp32.
// ---------------------------------------------------------------------------
__global__ __launch_bounds__(256) void attn_k(
    const unsigned short* __restrict__ q,
    const unsigned short* __restrict__ kp,
    unsigned short* __restrict__ msg)
{
    __shared__ __align__(16) float Ks[64 * 128];
    const int h = blockIdx.y;
    const size_t b = blockIdx.z;
    const int n = blockIdx.x * 256 + threadIdx.x;

    {
        const int tt = threadIdx.x;
        const int dh = tt >> 2, seg = (tt & 3) * 32;
        const unsigned short* src =
            kp + (b * 1024 + (size_t)(dh * 16 + h)) * 128 + seg;
#pragma unroll
        for (int i = 0; i < 32; ++i) Ks[dh * 128 + seg + i] = bf2f(src[i]);
    }
    __syncthreads();

    float qr[64];
    const unsigned short* qb = q + b * 1024 * 4096 + n;
#pragma unroll
    for (int dh = 0; dh < 64; ++dh)
        qr[dh] = bf2f(qb[(size_t)(dh * 16 + h) * 4096]);

    float acc[64];
#pragma unroll
    for (int dh = 0; dh < 64; ++dh) acc[dh] = 0.f;
    float lsum = 0.f;

    const float4* Ks4 = (const float4*)Ks;
#pragma unroll 1
    for (int kc = 0; kc < 32; ++kc) {
        float sx = 0.f, sy = 0.f, sz = 0.f, sw = 0.f;
#pragma unroll
        for (int dh = 0; dh < 64; ++dh) {
            const float4 kv = Ks4[dh * 32 + kc];  // wave-uniform -> broadcast
            sx = fmaf(qr[dh], kv.x, sx);
            sy = fmaf(qr[dh], kv.y, sy);
            sz = fmaf(qr[dh], kv.z, sz);
            sw = fmaf(qr[dh], kv.w, sw);
        }
        const float ex = __expf(sx * 0.125f), ey = __expf(sy * 0.125f);
        const float ez = __expf(sz * 0.125f), ew = __expf(sw * 0.125f);
        lsum += ex + ey + ez + ew;
        asm volatile("" ::: "memory");  // keep the two dh-loops separate
#pragma unroll
        for (int dh = 0; dh < 64; ++dh) {
            const float4 kv = Ks4[dh * 32 + kc];
            acc[dh] = fmaf(ex, kv.x, acc[dh]);
            acc[dh] = fmaf(ey, kv.y, acc[dh]);
            acc[dh] = fmaf(ez, kv.z, acc[dh]);
            acc[dh] = fmaf(ew, kv.w, acc[dh]);
        }
    }
    const float inv = 1.f / lsum;
    unsigned short* ob = msg + b * 1024 * 4096 + n;
#pragma unroll
    for (int dh = 0; dh < 64; ++dh)
        ob[(size_t)(dh * 16 + h) * 4096] = f2bf(acc[dh] * inv);
}

// ---------------------------------------------------------------------------
extern "C" void kernel_launch(void* const* d_in, const int* in_sizes, int n_in,
                              void* d_out, int out_size, void* d_ws, size_t ws_size,
                              hipStream_t stream)
{
    (void)in_sizes; (void)n_in; (void)out_size; (void)ws_size;
    const float* x    = (const float*)d_in[0];
    const float* srcp = (const float*)d_in[1];
    const float* Wq   = (const float*)d_in[2];
    const float* bq   = (const float*)d_in[3];
    const float* Wk   = (const float*)d_in[4];
    const float* bk   = (const float*)d_in[5];
    const float* proj = (const float*)d_in[6];
    const float* Wm   = (const float*)d_in[7];
    const float* bm   = (const float*)d_in[8];
    const float* W1   = (const float*)d_in[9];
    const float* b1   = (const float*)d_in[10];
    const float* gam  = (const float*)d_in[11];
    const float* bet  = (const float*)d_in[12];
    const float* mu   = (const float*)d_in[13];
    const float* var  = (const float*)d_in[14];
    const float* W2   = (const float*)d_in[15];
    const float* b2   = (const float*)d_in[16];
    float* out = (float*)d_out;
    unsigned short* ws = (unsigned short*)d_ws;

    const long long E = 16777216LL;  // 4*4096*1024
    unsigned short* xt   = ws;                 // bf16 x^T   [b][n][1024]
    unsigned short* st   = xt + E;             // bf16 src^T [b][n][1024]
    unsigned short* qc   = st + E;             // bf16 q     [b][1024][4096]
    unsigned short* kc   = qc + E;             // bf16 k     [b][1024][4096]
    unsigned short* ht   = kc + E;             // bf16 h^T   [b][n][2048]
    unsigned short* pT   = ht + 2 * E;         // bf16 proj^T [128][4096]
    unsigned short* kpb  = pT + 524288;        // bf16 kp    [b][1024][128]
    unsigned short* wqb  = kpb + 524288;       // bf16 weights
    unsigned short* wkb  = wqb + 1048576;
    unsigned short* wmb  = wkb + 1048576;
    unsigned short* w1b  = wmb + 1048576;
    unsigned short* w2b  = w1b + 4194304;
    // end = w2b + 2097152 = 111,149,056 shorts ~= 212 MiB
    unsigned short* msgc  = kc;  // alias: k dead after kp GEMM
    unsigned short* msgt  = qc;  // alias: q dead after attention
    unsigned short* msg2t = st;  // alias: src^T dead after k GEMM

    // --- dtype conversion + layout ---
    cvt_transpose<<<dim3(128, 32, 4), 256, 0, stream>>>(x,    xt, 1024, 4096);
    cvt_transpose<<<dim3(128, 32, 4), 256, 0, stream>>>(srcp, st, 1024, 4096);
    cvt_transpose<<<dim3(4, 128, 1), 256, 0, stream>>>(proj, pT, 4096, 128);
    cvt_flat<<<1024, 256, 0, stream>>>(Wq, wqb, 1048576);
    cvt_flat<<<1024, 256, 0, stream>>>(Wk, wkb, 1048576);
    cvt_flat<<<1024, 256, 0, stream>>>(Wm, wmb, 1048576);
    cvt_flat<<<4096, 256, 0, stream>>>(W1, w1b, 4194304);
    cvt_flat<<<2048, 256, 0, stream>>>(W2, w2b, 2097152);

    // q[b][o][n] = Wq . x + bq  (A=Wq, BT=x^T)
    gemm_bt<<<dim3(32, 8, 4), 256, 0, stream>>>(
        wqb, nullptr, 1024, xt, qc, nullptr, 1024, 1024, 1024, 4096,
        0LL, 4096LL * 1024, 1024LL * 4096, bq, nullptr,
        nullptr, nullptr, nullptr, nullptr);
    // k[b][o][n] = Wk . source + bk
    gemm_bt<<<dim3(32, 8, 4), 256, 0, stream>>>(
        wkb, nullptr, 1024, st, kc, nullptr, 1024, 1024, 1024, 4096,
        0LL, 4096LL * 1024, 1024LL * 4096, bk, nullptr,
        nullptr, nullptr, nullptr, nullptr);
    // kp[b][d][kk] = sum_m k[d][m] projT[kk][m]
    gemm_bt<<<dim3(1, 8, 4), 256, 0, stream>>>(
        kc, nullptr, 4096, pT, kpb, nullptr, 4096, 4096, 4096, 128,
        1024LL * 4096, 0LL, 1024LL * 128, nullptr, nullptr,
        nullptr, nullptr, nullptr, nullptr);
    // attention -> msg channel-major (overwrites k)
    attn_k<<<dim3(16, 16, 4), 256, 0, stream>>>(qc, kpb, msgc);
    // msg -> msg^T (into q's buffer)
    transpose_bf16<<<dim3(128, 32, 4), 256, 0, stream>>>(msgc, msgt, 1024, 4096);
    // msg2^T[n][o] = msg^T . Wm^T + bm
    gemm_bt<<<dim3(8, 32, 4), 256, 0, stream>>>(
        msgt, nullptr, 1024, wmb, msg2t, nullptr, 1024, 1024, 1024, 1024,
        4096LL * 1024, 0LL, 4096LL * 1024, nullptr, bm,
        nullptr, nullptr, nullptr, nullptr);
    // h^T[n][o2] = concat(x^T, msg2^T) . W1^T + b1, BN(eps=1e-3), ReLU
    gemm_bt<<<dim3(16, 32, 4), 256, 0, stream>>>(
        xt, msg2t, 1024, w1b, ht, nullptr, 2048, 1024, 2048, 2048,
        4096LL * 1024, 0LL, 4096LL * 2048, nullptr, b1,
        gam, bet, mu, var);
    // out[b][o][n] = W2 . h + b2   (f32 output)
    gemm_bt<<<dim3(32, 8, 4), 256, 0, stream>>>(
        w2b, nullptr, 2048, ht, nullptr, out, 2048, 2048, 2048, 4096,
        0LL, 4096LL * 2048, 1024LL * 4096, b2, nullptr,
        nullptr, nullptr, nullptr, nullptr);
}

// Round 3
// 898.774 us; speedup vs baseline: 1.3293x; 1.3293x over previous
//
#include <hip/hip_runtime.h>
#include <stdint.h>

typedef __bf16 bf16x8 __attribute__((ext_vector_type(8)));
typedef float f32x4 __attribute__((ext_vector_type(4)));

__device__ __forceinline__ unsigned short f2bf(float f) {
    union { float f; uint32_t i; } v;
    v.f = f;
    uint32_t x = v.i;
    return (unsigned short)((x + 0x7FFFu + ((x >> 16) & 1u)) >> 16);  // RNE
}

// async global->LDS, 16B per lane. LDS dest must be wave-uniform base + lane*16.
typedef __attribute__((address_space(3))) unsigned int lds_u32;
typedef __attribute__((address_space(1))) const unsigned int glob_u32;
__device__ __forceinline__ void gld16(const unsigned short* g, unsigned short* l) {
    __builtin_amdgcn_global_load_lds((glob_u32*)g, (lds_u32*)l, 16, 0, 0);
}

// ---------------------------------------------------------------------------
// Flat f32 -> bf16 (W1, W2). n % 1024 == 0.
// ---------------------------------------------------------------------------
__global__ __launch_bounds__(256) void cvt_flat(
    const float* __restrict__ in, unsigned short* __restrict__ out, int n)
{
    const int i = (blockIdx.x * 256 + threadIdx.x) * 4;
    if (i < n) {
        const float4 v = *(const float4*)(in + i);
        out[i + 0] = f2bf(v.x); out[i + 1] = f2bf(v.y);
        out[i + 2] = f2bf(v.z); out[i + 3] = f2bf(v.w);
    }
}

// Row-permuted f32->bf16 for 1024x1024 weights: out[o'][i] = in[perm(o')][i],
// perm(o') = (o'&63)*16 + (o'>>6)   (o = dh*16+h  ->  o' = h*64+dh)
__global__ __launch_bounds__(256) void cvt_permrow(
    const float* __restrict__ in, unsigned short* __restrict__ out)
{
    const int i = (blockIdx.x * 256 + threadIdx.x) * 4;
    const int row = i >> 10, col = i & 1023;
    const int src = ((row & 63) * 16 + (row >> 6)) * 1024 + col;
    const float4 v = *(const float4*)(in + src);
    out[i + 0] = f2bf(v.x); out[i + 1] = f2bf(v.y);
    out[i + 2] = f2bf(v.z); out[i + 3] = f2bf(v.w);
}

// Col-permuted f32->bf16 for 1024x1024 (Wm): out[o][i'] = in[o][perm(i')]
__global__ __launch_bounds__(256) void cvt_permcol(
    const float* __restrict__ in, unsigned short* __restrict__ out)
{
    const int i = (blockIdx.x * 256 + threadIdx.x) * 4;
    const int row = i >> 10, c0 = i & 1023;
    const float* r = in + (size_t)row * 1024;
#pragma unroll
    for (int j = 0; j < 4; ++j) {
        const int c = c0 + j;
        out[i + j] = f2bf(r[(c & 63) * 16 + (c >> 6)]);
    }
}

__global__ __launch_bounds__(256) void permute_bias2(
    const float* __restrict__ bq, const float* __restrict__ bk,
    float* __restrict__ bqp, float* __restrict__ bkp)
{
    const int o = blockIdx.x * 256 + threadIdx.x;  // 1024
    const int src = (o & 63) * 16 + (o >> 6);
    bqp[o] = bq[src];
    bkp[o] = bk[src];
}

// ---------------------------------------------------------------------------
// f32 [R][C] -> bf16 [C][R], batched over blockIdx.z. R,C multiples of 32.
// ---------------------------------------------------------------------------
__global__ __launch_bounds__(256) void cvt_transpose(
    const float* __restrict__ in, unsigned short* __restrict__ out,
    int R, int C)
{
    __shared__ unsigned short tile[32][33];
    const size_t bo = (size_t)blockIdx.z * R * C;
    const int c0 = blockIdx.x * 32, r0 = blockIdx.y * 32;
    const int tx = threadIdx.x & 31, ty = threadIdx.x >> 5;
#pragma unroll
    for (int i = 0; i < 4; ++i)
        tile[ty + i * 8][tx] = f2bf(in[bo + (size_t)(r0 + ty + i * 8) * C + (c0 + tx)]);
    __syncthreads();
#pragma unroll
    for (int i = 0; i < 4; ++i)
        out[bo + (size_t)(c0 + ty + i * 8) * R + (r0 + tx)] = tile[tx][ty + i * 8];
}

// ---------------------------------------------------------------------------
// C[m][n'] = sum_k A[m][k]*BT[n'][k], bf16 in / f32 acc. 128x128 tile, BK=32,
// m97-style global_load_lds staging (unpadded SA=32; LDS layout IS lane order).
// ---------------------------------------------------------------------------
__global__ __launch_bounds__(256) void gemm_bt(
    const unsigned short* __restrict__ A,
    const unsigned short* __restrict__ A2, int K1,
    const unsigned short* __restrict__ BT,
    unsigned short* __restrict__ C, float* __restrict__ Cf,
    int Kdim, int lda, int ldb, int ldc,
    long long strideA, long long strideB, long long strideC,
    const float* __restrict__ bias_m,
    const float* __restrict__ bias_n,
    const float* __restrict__ bn_g,
    const float* __restrict__ bn_b,
    const float* __restrict__ bn_mu,
    const float* __restrict__ bn_var)
{
    __shared__ __align__(16) unsigned short As[128 * 32];
    __shared__ __align__(16) unsigned short Bs[128 * 32];

    const int m0 = blockIdx.y * 128, n0 = blockIdx.x * 128;
    const unsigned short* Ab  = A + (size_t)blockIdx.z * strideA;
    const unsigned short* A2b = A2 ? A2 + (size_t)blockIdx.z * strideA
                                   : (const unsigned short*)0;
    const unsigned short* Bb = BT + (size_t)blockIdx.z * strideB;

    const int t = threadIdx.x;
    const int lane = t & 63, wid = t >> 6;
    const int wm = wid >> 1, wn = wid & 1;
    const int r16 = lane & 15, quad = lane >> 4;

    f32x4 acc[4][4];
    const f32x4 zf = {0.f, 0.f, 0.f, 0.f};
#pragma unroll
    for (int i = 0; i < 4; ++i)
#pragma unroll
        for (int j = 0; j < 4; ++j) acc[i][j] = zf;

    for (int kt = 0; kt < Kdim; kt += 32) {
        const unsigned short* Asrc;
        int kk;
        if (kt < K1) { Asrc = Ab; kk = kt; } else { Asrc = A2b; kk = kt - K1; }
#pragma unroll
        for (int c = 0; c < 2; ++c) {
            const int ch = c * 256 + t;
            const int row = ch >> 2, k8 = (ch & 3) * 8;
            gld16(&Asrc[(size_t)(m0 + row) * lda + kk + k8], &As[ch * 8]);
            gld16(&Bb[(size_t)(n0 + row) * ldb + kt + k8], &Bs[ch * 8]);
        }
        __syncthreads();
        bf16x8 af[4], bfb[4];
#pragma unroll
        for (int i = 0; i < 4; ++i) {
            af[i]  = *(const bf16x8*)(&As[(wm * 64 + i * 16 + r16) * 32 + quad * 8]);
            bfb[i] = *(const bf16x8*)(&Bs[(wn * 64 + i * 16 + r16) * 32 + quad * 8]);
        }
#pragma unroll
        for (int mi = 0; mi < 4; ++mi)
#pragma unroll
            for (int ni = 0; ni < 4; ++ni)
                acc[mi][ni] = __builtin_amdgcn_mfma_f32_16x16x32_bf16(
                    af[mi], bfb[ni], acc[mi][ni], 0, 0, 0);
        __syncthreads();
    }

    unsigned short* Cb = C ? C + (size_t)blockIdx.z * strideC : (unsigned short*)0;
    float* Cfb = Cf ? Cf + (size_t)blockIdx.z * strideC : (float*)0;
    const bool has_bn = (bn_g != 0);
#pragma unroll
    for (int ni = 0; ni < 4; ++ni) {
        const int gn = n0 + wn * 64 + ni * 16 + r16;
        const float addn = bias_n ? bias_n[gn] : 0.f;
        float g = 1.f, bb = 0.f, mu = 0.f, rstd = 1.f;
        if (has_bn) {
            g = bn_g[gn]; bb = bn_b[gn]; mu = bn_mu[gn];
            rstd = rsqrtf(bn_var[gn] + 1e-3f);
        }
#pragma unroll
        for (int mi = 0; mi < 4; ++mi) {
            const int gm0 = m0 + wm * 64 + mi * 16 + quad * 4;
#pragma unroll
            for (int r = 0; r < 4; ++r) {
                float v = acc[mi][ni][r] + addn;
                if (bias_m) v += bias_m[gm0 + r];
                if (has_bn) { v = g * (v - mu) * rstd + bb; v = fmaxf(v, 0.f); }
                const size_t idx = (size_t)(gm0 + r) * ldc + gn;
                if (Cfb) Cfb[idx] = v;
                else     Cb[idx]  = f2bf(v);
            }
        }
    }
}

// ---------------------------------------------------------------------------
// MFMA flash-attention. Channel order o' = h*64+dh (permuted at weight-cvt).
// qT  [b][4096][1024] bf16, head h = cols [h*64, h*64+64)
// kp  [b][1024][128]  bf16, rows h*64+dh = per-head [64dh][128kk] block (V layout)
// msgT[b][4096][1024] bf16 out (may alias qT: block writes exactly what it read)
// Block = one (b, h, 128-row n-tile); 4 waves, wave w owns n rows [w*32,w*32+32).
// S = Q.K^T (dh-contract) -> softmax in-register (shuffle over r16 group) ->
// P ->LDS (A-frag layout) -> PV (kk-contract, V = staged kp rows) -> msgT.
// ---------------------------------------------------------------------------
__global__ __launch_bounds__(256) void attn_fused(
    const unsigned short* __restrict__ qT,
    const unsigned short* __restrict__ kp,
    unsigned short* __restrict__ msgT)
{
    constexpr int QS = 72, KS = 72, VS = 136, PS = 136;
    __shared__ __align__(16) unsigned short QKP[128 * QS + 128 * KS];  // Ps aliases
    __shared__ __align__(16) unsigned short Vs[64 * VS];
    unsigned short* Qs = QKP;            // [n][dh]   pad 72
    unsigned short* Ks = QKP + 128 * QS; // [kk][dh]  pad 72
    unsigned short* Ps = QKP;            // [n][kk]   pad 136 (17408 <= 18432)

    const int t = threadIdx.x;
    const int lane = t & 63, w = t >> 6;
    const int r16 = lane & 15, quad = lane >> 4;
    const int h = blockIdx.y, n0 = blockIdx.x * 128;
    const size_t b = blockIdx.z;

    const unsigned short* qbase = qT + (b * 4096 + n0) * 1024 + h * 64;
    const unsigned short* kbase = kp + (b * 1024 + h * 64) * 128;

    // stage Q [128n][64dh]: 1024 16B chunks, coalesced (8 chunks = one row)
#pragma unroll
    for (int i = 0; i < 4; ++i) {
        const int c = i * 256 + t;
        const int n = c >> 3, dh0 = (c & 7) * 8;
        *(int4*)&Qs[n * QS + dh0] = *(const int4*)&qbase[(size_t)n * 1024 + dh0];
    }
    // stage K/V from kp rows (one global read -> Vs direct + Ks transposed)
#pragma unroll
    for (int i = 0; i < 4; ++i) {
        const int c = i * 256 + t;
        const int kkq = c & 3, dh = (c >> 2) & 63, kkh = c >> 8;
        const int kk0 = kkh * 32 + kkq * 8;
        const bf16x8 v = *(const bf16x8*)&kbase[(size_t)dh * 128 + kk0];
        *(bf16x8*)&Vs[dh * VS + kk0] = v;
        const unsigned short* vs = (const unsigned short*)&v;
#pragma unroll
        for (int j = 0; j < 8; ++j) Ks[(kk0 + j) * KS + dh] = vs[j];
    }
    __syncthreads();

    // S = Q.K^T : wave w -> rows [w*32, w*32+32), all 128 kk
    f32x4 S[2][8];
    const f32x4 zf = {0.f, 0.f, 0.f, 0.f};
#pragma unroll
    for (int mi = 0; mi < 2; ++mi)
#pragma unroll
        for (int ni = 0; ni < 8; ++ni) S[mi][ni] = zf;

    bf16x8 aq[2][2];
#pragma unroll
    for (int mi = 0; mi < 2; ++mi)
#pragma unroll
        for (int ks = 0; ks < 2; ++ks)
            aq[mi][ks] = *(const bf16x8*)&Qs[(w * 32 + mi * 16 + r16) * QS + ks * 32 + quad * 8];
#pragma unroll
    for (int ni = 0; ni < 8; ++ni) {
        const bf16x8 b0 = *(const bf16x8*)&Ks[(ni * 16 + r16) * KS + quad * 8];
        const bf16x8 b1 = *(const bf16x8*)&Ks[(ni * 16 + r16) * KS + 32 + quad * 8];
#pragma unroll
        for (int mi = 0; mi < 2; ++mi) {
            S[mi][ni] = __builtin_amdgcn_mfma_f32_16x16x32_bf16(aq[mi][0], b0, S[mi][ni], 0, 0, 0);
            S[mi][ni] = __builtin_amdgcn_mfma_f32_16x16x32_bf16(aq[mi][1], b1, S[mi][ni], 0, 0, 0);
        }
    }

    __syncthreads();  // all waves done reading Qs/Ks before Ps overwrite

    // softmax (no max-sub: |S/8| < ~6, fp32-safe) + P -> LDS in A-frag layout
    float linv[2][4];
#pragma unroll
    for (int mi = 0; mi < 2; ++mi) {
        float e[8][4];
        float rs0 = 0.f, rs1 = 0.f, rs2 = 0.f, rs3 = 0.f;
#pragma unroll
        for (int ni = 0; ni < 8; ++ni) {
            e[ni][0] = __expf(S[mi][ni][0] * 0.125f); rs0 += e[ni][0];
            e[ni][1] = __expf(S[mi][ni][1] * 0.125f); rs1 += e[ni][1];
            e[ni][2] = __expf(S[mi][ni][2] * 0.125f); rs2 += e[ni][2];
            e[ni][3] = __expf(S[mi][ni][3] * 0.125f); rs3 += e[ni][3];
        }
        float rs[4] = {rs0, rs1, rs2, rs3};
#pragma unroll
        for (int r = 0; r < 4; ++r) {
            float s = rs[r];
            s += __shfl_xor(s, 1); s += __shfl_xor(s, 2);
            s += __shfl_xor(s, 4); s += __shfl_xor(s, 8);
            linv[mi][r] = 1.f / s;
        }
#pragma unroll
        for (int ni = 0; ni < 8; ++ni)
#pragma unroll
            for (int r = 0; r < 4; ++r)
                Ps[(w * 32 + mi * 16 + quad * 4 + r) * PS + ni * 16 + r16] = f2bf(e[ni][r]);
    }
    __syncthreads();

    // O = P.V : contraction over kk=128 (4 k-steps), V rows = dh
    f32x4 O[2][4];
#pragma unroll
    for (int mi = 0; mi < 2; ++mi)
#pragma unroll
        for (int ni = 0; ni < 4; ++ni) O[mi][ni] = zf;

    bf16x8 ap[2][4];
#pragma unroll
    for (int mi = 0; mi < 2; ++mi)
#pragma unroll
        for (int ks = 0; ks < 4; ++ks)
            ap[mi][ks] = *(const bf16x8*)&Ps[(w * 32 + mi * 16 + r16) * PS + ks * 32 + quad * 8];
#pragma unroll
    for (int ni = 0; ni < 4; ++ni)
#pragma unroll
        for (int ks = 0; ks < 4; ++ks) {
            const bf16x8 bv = *(const bf16x8*)&Vs[(ni * 16 + r16) * VS + ks * 32 + quad * 8];
#pragma unroll
            for (int mi = 0; mi < 2; ++mi)
                O[mi][ni] = __builtin_amdgcn_mfma_f32_16x16x32_bf16(ap[mi][ks], bv, O[mi][ni], 0, 0, 0);
        }

    unsigned short* ob = msgT + (b * 4096 + n0) * 1024 + h * 64;
#pragma unroll
    for (int mi = 0; mi < 2; ++mi)
#pragma unroll
        for (int ni = 0; ni < 4; ++ni)
#pragma unroll
            for (int r = 0; r < 4; ++r)
                ob[(size_t)(w * 32 + mi * 16 + quad * 4 + r) * 1024 + ni * 16 + r16] =
                    f2bf(O[mi][ni][r] * linv[mi][r]);
}

// ---------------------------------------------------------------------------
extern "C" void kernel_launch(void* const* d_in, const int* in_sizes, int n_in,
                              void* d_out, int out_size, void* d_ws, size_t ws_size,
                              hipStream_t stream)
{
    (void)in_sizes; (void)n_in; (void)out_size; (void)ws_size;
    const float* x    = (const float*)d_in[0];
    const float* srcp = (const float*)d_in[1];
    const float* Wq   = (const float*)d_in[2];
    const float* bq   = (const float*)d_in[3];
    const float* Wk   = (const float*)d_in[4];
    const float* bk   = (const float*)d_in[5];
    const float* proj = (const float*)d_in[6];
    const float* Wm   = (const float*)d_in[7];
    const float* bm   = (const float*)d_in[8];
    const float* W1   = (const float*)d_in[9];
    const float* b1   = (const float*)d_in[10];
    const float* gam  = (const float*)d_in[11];
    const float* bet  = (const float*)d_in[12];
    const float* mu   = (const float*)d_in[13];
    const float* var  = (const float*)d_in[14];
    const float* W2   = (const float*)d_in[15];
    const float* b2   = (const float*)d_in[16];
    float* out = (float*)d_out;
    unsigned short* ws = (unsigned short*)d_ws;

    const long long E = 16777216LL;  // 4*4096*1024
    unsigned short* xt  = ws;                  // bf16 x^T   [b][n][1024] (orig order)
    unsigned short* st  = xt + E;              // bf16 src^T; later msg2^T
    unsigned short* qt  = st + E;              // bf16 q^T [b][n][o'] ; msgT in-place
    unsigned short* kc  = qt + E;              // bf16 k' [b][o'][m]
    unsigned short* ht  = kc + E;              // bf16 h^T [b][n][2048]
    unsigned short* pT  = ht + 2 * E;          // bf16 proj^T [128][4096]
    unsigned short* kpb = pT + 524288;         // bf16 kp' [b][o'][128]
    unsigned short* wqb = kpb + 524288;        // row-permuted
    unsigned short* wkb = wqb + 1048576;       // row-permuted
    unsigned short* wmb = wkb + 1048576;       // col-permuted
    unsigned short* w1b = wmb + 1048576;
    unsigned short* w2b = w1b + 4194304;
    float* bqp = (float*)(w2b + 2097152);      // 1024 f32
    float* bkp = bqp + 1024;                   // 1024 f32

    // --- dtype conversion + layout (+ head-major channel permutation) ---
    cvt_transpose<<<dim3(128, 32, 4), 256, 0, stream>>>(x,    xt, 1024, 4096);
    cvt_transpose<<<dim3(128, 32, 4), 256, 0, stream>>>(srcp, st, 1024, 4096);
    cvt_transpose<<<dim3(4, 128, 1), 256, 0, stream>>>(proj, pT, 4096, 128);
    cvt_permrow<<<1024, 256, 0, stream>>>(Wq, wqb);
    cvt_permrow<<<1024, 256, 0, stream>>>(Wk, wkb);
    cvt_permcol<<<1024, 256, 0, stream>>>(Wm, wmb);
    cvt_flat<<<4096, 256, 0, stream>>>(W1, w1b, 4194304);
    cvt_flat<<<2048, 256, 0, stream>>>(W2, w2b, 2097152);
    permute_bias2<<<4, 256, 0, stream>>>(bq, bk, bqp, bkp);

    // q^T[b][n][o'] = x^T . Wq'^T + bq'   (n-major out)
    gemm_bt<<<dim3(8, 32, 4), 256, 0, stream>>>(
        xt, nullptr, 1024, wqb, qt, nullptr, 1024, 1024, 1024, 1024,
        4096LL * 1024, 0LL, 4096LL * 1024, nullptr, bqp,
        nullptr, nullptr, nullptr, nullptr);
    // k'[b][o'][m] = Wk' . source + bk'   (channel-major out)
    gemm_bt<<<dim3(32, 8, 4), 256, 0, stream>>>(
        wkb, nullptr, 1024, st, kc, nullptr, 1024, 1024, 1024, 4096,
        0LL, 4096LL * 1024, 1024LL * 4096, bkp, nullptr,
        nullptr, nullptr, nullptr, nullptr);
    // kp'[b][o'][kk] = sum_m k'[o'][m] projT[kk][m]
    gemm_bt<<<dim3(1, 8, 4), 256, 0, stream>>>(
        kc, nullptr, 4096, pT, kpb, nullptr, 4096, 4096, 4096, 128,
        1024LL * 4096, 0LL, 1024LL * 128, nullptr, nullptr,
        nullptr, nullptr, nullptr, nullptr);
    // fused MFMA attention (in-place: msgT overwrites qT)
    attn_fused<<<dim3(32, 16, 4), 256, 0, stream>>>(qt, kpb, qt);
    // msg2^T[n][o2] = msgT . Wm'^T + bm
    gemm_bt<<<dim3(8, 32, 4), 256, 0, stream>>>(
        qt, nullptr, 1024, wmb, st, nullptr, 1024, 1024, 1024, 1024,
        4096LL * 1024, 0LL, 4096LL * 1024, nullptr, bm,
        nullptr, nullptr, nullptr, nullptr);
    // h^T[n][o2] = concat(x^T, msg2^T) . W1^T + b1, BN(eps=1e-3), ReLU
    gemm_bt<<<dim3(16, 32, 4), 256, 0, stream>>>(
        xt, st, 1024, w1b, ht, nullptr, 2048, 1024, 2048, 2048,
        4096LL * 1024, 0LL, 4096LL * 2048, nullptr, b1,
        gam, bet, mu, var);
    // out[b][o][n] = W2 . h + b2  (f32 out)
    gemm_bt<<<dim3(32, 8, 4), 256, 0, stream>>>(
        w2b, nullptr, 2048, ht, nullptr, out, 2048, 2048, 2048, 4096,
        0LL, 4096LL * 2048, 1024LL * 4096, b2, nullptr,
        nullptr, nullptr, nullptr, nullptr);
}

// Round 4
// 738.575 us; speedup vs baseline: 1.6176x; 1.2169x over previous
//
#include <hip/hip_runtime.h>
#include <stdint.h>

typedef __bf16 bf16x8 __attribute__((ext_vector_type(8)));
typedef float f32x4 __attribute__((ext_vector_type(4)));

__device__ __forceinline__ unsigned short f2bf(float f) {
    union { float f; uint32_t i; } v;
    v.f = f;
    uint32_t x = v.i;
    return (unsigned short)((x + 0x7FFFu + ((x >> 16) & 1u)) >> 16);  // RNE
}

// async global->LDS, 16B per lane. LDS dest is wave-uniform base + lane*16;
// the GLOBAL source address is per-lane free (this is what enables swizzling).
typedef __attribute__((address_space(3))) unsigned int lds_u32;
typedef __attribute__((address_space(1))) const unsigned int glob_u32;
__device__ __forceinline__ void gld16(const unsigned short* g, unsigned short* l) {
    __builtin_amdgcn_global_load_lds((glob_u32*)g, (lds_u32*)l, 16, 0, 0);
}

// ---------------------------------------------------------------------------
// All weight prep in ONE launch (range-dispatch on blockIdx.x, 9220 blocks).
// ---------------------------------------------------------------------------
__global__ __launch_bounds__(256) void prep_weights(
    const float* __restrict__ Wq, const float* __restrict__ Wk,
    const float* __restrict__ Wm, const float* __restrict__ W1,
    const float* __restrict__ W2, const float* __restrict__ bq,
    const float* __restrict__ bk,
    unsigned short* __restrict__ wqb, unsigned short* __restrict__ wkb,
    unsigned short* __restrict__ wmb, unsigned short* __restrict__ w1b,
    unsigned short* __restrict__ w2b, float* __restrict__ bqp,
    float* __restrict__ bkp)
{
    const int b = blockIdx.x, t = threadIdx.x;
    if (b < 2048) {
        const float* in = (b < 1024) ? Wq : Wk;
        unsigned short* out = (b < 1024) ? wqb : wkb;
        const int i = ((b & 1023) * 256 + t) * 4;
        const int row = i >> 10, col = i & 1023;
        const float4 v = *(const float4*)(in + ((row & 63) * 16 + (row >> 6)) * 1024 + col);
        out[i + 0] = f2bf(v.x); out[i + 1] = f2bf(v.y);
        out[i + 2] = f2bf(v.z); out[i + 3] = f2bf(v.w);
    } else if (b < 3072) {
        const int i = ((b - 2048) * 256 + t) * 4;
        const int row = i >> 10, c0 = i & 1023;
        const float* r = Wm + (size_t)row * 1024;
#pragma unroll
        for (int j = 0; j < 4; ++j) {
            const int c = c0 + j;
            wmb[i + j] = f2bf(r[(c & 63) * 16 + (c >> 6)]);
        }
    } else if (b < 7168) {
        const int i = ((b - 3072) * 256 + t) * 4;
        const float4 v = *(const float4*)(W1 + i);
        w1b[i + 0] = f2bf(v.x); w1b[i + 1] = f2bf(v.y);
        w1b[i + 2] = f2bf(v.z); w1b[i + 3] = f2bf(v.w);
    } else if (b < 9216) {
        const int i = ((b - 7168) * 256 + t) * 4;
        const float4 v = *(const float4*)(W2 + i);
        w2b[i + 0] = f2bf(v.x); w2b[i + 1] = f2bf(v.y);
        w2b[i + 2] = f2bf(v.z); w2b[i + 3] = f2bf(v.w);
    } else {
        const int o = (b - 9216) * 256 + t;
        const int src = (o & 63) * 16 + (o >> 6);
        bqp[o] = bq[src];
        bkp[o] = bk[src];
    }
}

// ---------------------------------------------------------------------------
// f32 [R][C] -> bf16 [C][R], batched over blockIdx.z (proj).
// ---------------------------------------------------------------------------
__global__ __launch_bounds__(256) void cvt_transpose(
    const float* __restrict__ in, unsigned short* __restrict__ out,
    int R, int C)
{
    __shared__ unsigned short tile[32][33];
    const size_t bo = (size_t)blockIdx.z * R * C;
    const int c0 = blockIdx.x * 32, r0 = blockIdx.y * 32;
    const int tx = threadIdx.x & 31, ty = threadIdx.x >> 5;
#pragma unroll
    for (int i = 0; i < 4; ++i)
        tile[ty + i * 8][tx] = f2bf(in[bo + (size_t)(r0 + ty + i * 8) * C + (c0 + tx)]);
    __syncthreads();
#pragma unroll
    for (int i = 0; i < 4; ++i)
        out[bo + (size_t)(c0 + ty + i * 8) * R + (r0 + tx)] = tile[tx][ty + i * 8];
}

// Fused x + source transpose: z = tensor*4 + batch.
__global__ __launch_bounds__(256) void cvt_transpose_xs(
    const float* __restrict__ x, const float* __restrict__ s,
    unsigned short* __restrict__ xt, unsigned short* __restrict__ st)
{
    __shared__ unsigned short tile[32][33];
    const int z = blockIdx.z;
    const float* in = (z < 4) ? x : s;
    unsigned short* out = (z < 4) ? xt : st;
    const size_t bo = (size_t)(z & 3) * 1024 * 4096;
    const int c0 = blockIdx.x * 32, r0 = blockIdx.y * 32;
    const int tx = threadIdx.x & 31, ty = threadIdx.x >> 5;
#pragma unroll
    for (int i = 0; i < 4; ++i)
        tile[ty + i * 8][tx] = f2bf(in[bo + (size_t)(r0 + ty + i * 8) * 4096 + (c0 + tx)]);
    __syncthreads();
#pragma unroll
    for (int i = 0; i < 4; ++i)
        out[bo + (size_t)(c0 + ty + i * 8) * 1024 + (r0 + tx)] = tile[tx][ty + i * 8];
}

// ---------------------------------------------------------------------------
// C[m][n'] = sum_k A[m][k]*BT[n'][k], bf16 in / f32 acc. 128x128 tile, BK=64.
// global_load_lds staging with XOR chunk swizzle (slot = k16 ^ (row&7)):
// fragment ds_read_b128s spread over all 8 chunk slots -> <=2-way banks (free).
// SPLIT>1: k-range split across z; f32 partial written to Cf + z*strideC.
// CONCAT: A supplies k<K1, A2 k>=K1 (K1 % 64 == 0).
// ---------------------------------------------------------------------------
template<int LDA, int LDB, int LDC, int KD, int SPLIT, bool CONCAT>
__global__ __launch_bounds__(256) void gemm_bt(
    const unsigned short* __restrict__ A,
    const unsigned short* __restrict__ A2, int K1,
    const unsigned short* __restrict__ BT,
    unsigned short* __restrict__ C, float* __restrict__ Cf,
    long long strideA, long long strideB, long long strideC,
    const float* __restrict__ bias_m,
    const float* __restrict__ bias_n,
    const float* __restrict__ bn_g,
    const float* __restrict__ bn_b,
    const float* __restrict__ bn_mu,
    const float* __restrict__ bn_var)
{
    constexpr int KPB = KD / SPLIT;
    __shared__ __align__(16) unsigned short As[128 * 64];
    __shared__ __align__(16) unsigned short Bs[128 * 64];

    const int z = blockIdx.z;
    const int batch = z / SPLIT;
    const int kbase = (z % SPLIT) * KPB;
    const int m0 = blockIdx.y * 128, n0 = blockIdx.x * 128;
    const unsigned short* Ab  = A + (size_t)batch * strideA;
    const unsigned short* A2b = CONCAT ? A2 + (size_t)batch * strideA
                                       : (const unsigned short*)0;
    const unsigned short* Bb = BT + (size_t)batch * strideB;

    const int t = threadIdx.x;
    const int lane = t & 63, wid = t >> 6;
    const int wm = wid >> 1, wn = wid & 1;
    const int r16 = lane & 15, quad = lane >> 4;

    f32x4 acc[4][4];
    const f32x4 zf = {0.f, 0.f, 0.f, 0.f};
#pragma unroll
    for (int i = 0; i < 4; ++i)
#pragma unroll
        for (int j = 0; j < 4; ++j) acc[i][j] = zf;

    for (int kt = kbase; kt < kbase + KPB; kt += 64) {
        const unsigned short* Asrc = Ab;
        int kk = kt;
        if (CONCAT && kt >= K1) { Asrc = A2b; kk = kt - K1; }
#pragma unroll
        for (int i = 0; i < 4; ++i) {
            const int p = i * 256 + t;
            const int row = p >> 3, slot = p & 7;
            const int kc = (slot ^ (row & 7)) * 8;
            gld16(&Asrc[(size_t)(m0 + row) * LDA + kk + kc], &As[p * 8]);
            gld16(&Bb[(size_t)(n0 + row) * LDB + kt + kc], &Bs[p * 8]);
        }
        __syncthreads();
#pragma unroll
        for (int s = 0; s < 2; ++s) {
            bf16x8 af[4], bfb[4];
#pragma unroll
            for (int i = 0; i < 4; ++i) {
                const int ra = wm * 64 + i * 16 + r16;
                const int rb = wn * 64 + i * 16 + r16;
                af[i]  = *(const bf16x8*)&As[(ra * 8 + ((s * 4 + quad) ^ (ra & 7))) * 8];
                bfb[i] = *(const bf16x8*)&Bs[(rb * 8 + ((s * 4 + quad) ^ (rb & 7))) * 8];
            }
#pragma unroll
            for (int mi = 0; mi < 4; ++mi)
#pragma unroll
                for (int ni = 0; ni < 4; ++ni)
                    acc[mi][ni] = __builtin_amdgcn_mfma_f32_16x16x32_bf16(
                        af[mi], bfb[ni], acc[mi][ni], 0, 0, 0);
        }
        __syncthreads();
    }

    unsigned short* Cb = C ? C + (size_t)z * strideC : (unsigned short*)0;
    float* Cfb = Cf ? Cf + (size_t)z * strideC : (float*)0;
    const bool has_bn = (bn_g != 0);
#pragma unroll
    for (int ni = 0; ni < 4; ++ni) {
        const int gn = n0 + wn * 64 + ni * 16 + r16;
        const float addn = bias_n ? bias_n[gn] : 0.f;
        float g = 1.f, bb = 0.f, mu = 0.f, rstd = 1.f;
        if (has_bn) {
            g = bn_g[gn]; bb = bn_b[gn]; mu = bn_mu[gn];
            rstd = rsqrtf(bn_var[gn] + 1e-3f);
        }
#pragma unroll
        for (int mi = 0; mi < 4; ++mi) {
            const int gm0 = m0 + wm * 64 + mi * 16 + quad * 4;
#pragma unroll
            for (int r = 0; r < 4; ++r) {
                float v = acc[mi][ni][r] + addn;
                if (bias_m) v += bias_m[gm0 + r];
                if (has_bn) { v = g * (v - mu) * rstd + bb; v = fmaxf(v, 0.f); }
                const size_t idx = (size_t)(gm0 + r) * LDC + gn;
                if (Cfb) Cfb[idx] = v;
                else     Cb[idx]  = f2bf(v);
            }
        }
    }
}

// kp split-K reduce: kpb[b][j] = bf16( sum_p acc[b*8+p][j] )
__global__ __launch_bounds__(256) void reduce_kp(
    const float* __restrict__ acc, unsigned short* __restrict__ kpb)
{
    const int j = (blockIdx.x * 256 + threadIdx.x) * 4;
    const int b = j >> 17, jj = j & 131071;
    const float* base = acc + (size_t)b * 8 * 131072 + jj;
    float4 s = *(const float4*)base;
#pragma unroll
    for (int p = 1; p < 8; ++p) {
        const float4 v = *(const float4*)(base + (size_t)p * 131072);
        s.x += v.x; s.y += v.y; s.z += v.z; s.w += v.w;
    }
    kpb[j + 0] = f2bf(s.x); kpb[j + 1] = f2bf(s.y);
    kpb[j + 2] = f2bf(s.z); kpb[j + 3] = f2bf(s.w);
}

// ---------------------------------------------------------------------------
// MFMA flash-attention (unchanged from round 3; channel order o' = h*64+dh).
// ---------------------------------------------------------------------------
__global__ __launch_bounds__(256) void attn_fused(
    const unsigned short* __restrict__ qT,
    const unsigned short* __restrict__ kp,
    unsigned short* __restrict__ msgT)
{
    constexpr int QS = 72, KS = 72, VS = 136, PS = 136;
    __shared__ __align__(16) unsigned short QKP[128 * QS + 128 * KS];
    __shared__ __align__(16) unsigned short Vs[64 * VS];
    unsigned short* Qs = QKP;
    unsigned short* Ks = QKP + 128 * QS;
    unsigned short* Ps = QKP;

    const int t = threadIdx.x;
    const int lane = t & 63, w = t >> 6;
    const int r16 = lane & 15, quad = lane >> 4;
    const int h = blockIdx.y, n0 = blockIdx.x * 128;
    const size_t b = blockIdx.z;

    const unsigned short* qbase = qT + (b * 4096 + n0) * 1024 + h * 64;
    const unsigned short* kbase = kp + (b * 1024 + h * 64) * 128;

#pragma unroll
    for (int i = 0; i < 4; ++i) {
        const int c = i * 256 + t;
        const int n = c >> 3, dh0 = (c & 7) * 8;
        *(int4*)&Qs[n * QS + dh0] = *(const int4*)&qbase[(size_t)n * 1024 + dh0];
    }
#pragma unroll
    for (int i = 0; i < 4; ++i) {
        const int c = i * 256 + t;
        const int kkq = c & 3, dh = (c >> 2) & 63, kkh = c >> 8;
        const int kk0 = kkh * 32 + kkq * 8;
        const bf16x8 v = *(const bf16x8*)&kbase[(size_t)dh * 128 + kk0];
        *(bf16x8*)&Vs[dh * VS + kk0] = v;
        const unsigned short* vs = (const unsigned short*)&v;
#pragma unroll
        for (int j = 0; j < 8; ++j) Ks[(kk0 + j) * KS + dh] = vs[j];
    }
    __syncthreads();

    f32x4 S[2][8];
    const f32x4 zf = {0.f, 0.f, 0.f, 0.f};
#pragma unroll
    for (int mi = 0; mi < 2; ++mi)
#pragma unroll
        for (int ni = 0; ni < 8; ++ni) S[mi][ni] = zf;

    bf16x8 aq[2][2];
#pragma unroll
    for (int mi = 0; mi < 2; ++mi)
#pragma unroll
        for (int ks = 0; ks < 2; ++ks)
            aq[mi][ks] = *(const bf16x8*)&Qs[(w * 32 + mi * 16 + r16) * QS + ks * 32 + quad * 8];
#pragma unroll
    for (int ni = 0; ni < 8; ++ni) {
        const bf16x8 b0 = *(const bf16x8*)&Ks[(ni * 16 + r16) * KS + quad * 8];
        const bf16x8 b1 = *(const bf16x8*)&Ks[(ni * 16 + r16) * KS + 32 + quad * 8];
#pragma unroll
        for (int mi = 0; mi < 2; ++mi) {
            S[mi][ni] = __builtin_amdgcn_mfma_f32_16x16x32_bf16(aq[mi][0], b0, S[mi][ni], 0, 0, 0);
            S[mi][ni] = __builtin_amdgcn_mfma_f32_16x16x32_bf16(aq[mi][1], b1, S[mi][ni], 0, 0, 0);
        }
    }

    __syncthreads();

    float linv[2][4];
#pragma unroll
    for (int mi = 0; mi < 2; ++mi) {
        float e[8][4];
        float rs0 = 0.f, rs1 = 0.f, rs2 = 0.f, rs3 = 0.f;
#pragma unroll
        for (int ni = 0; ni < 8; ++ni) {
            e[ni][0] = __expf(S[mi][ni][0] * 0.125f); rs0 += e[ni][0];
            e[ni][1] = __expf(S[mi][ni][1] * 0.125f); rs1 += e[ni][1];
            e[ni][2] = __expf(S[mi][ni][2] * 0.125f); rs2 += e[ni][2];
            e[ni][3] = __expf(S[mi][ni][3] * 0.125f); rs3 += e[ni][3];
        }
        float rs[4] = {rs0, rs1, rs2, rs3};
#pragma unroll
        for (int r = 0; r < 4; ++r) {
            float s = rs[r];
            s += __shfl_xor(s, 1); s += __shfl_xor(s, 2);
            s += __shfl_xor(s, 4); s += __shfl_xor(s, 8);
            linv[mi][r] = 1.f / s;
        }
#pragma unroll
        for (int ni = 0; ni < 8; ++ni)
#pragma unroll
            for (int r = 0; r < 4; ++r)
                Ps[(w * 32 + mi * 16 + quad * 4 + r) * PS + ni * 16 + r16] = f2bf(e[ni][r]);
    }
    __syncthreads();

    f32x4 O[2][4];
#pragma unroll
    for (int mi = 0; mi < 2; ++mi)
#pragma unroll
        for (int ni = 0; ni < 4; ++ni) O[mi][ni] = zf;

    bf16x8 ap[2][4];
#pragma unroll
    for (int mi = 0; mi < 2; ++mi)
#pragma unroll
        for (int ks = 0; ks < 4; ++ks)
            ap[mi][ks] = *(const bf16x8*)&Ps[(w * 32 + mi * 16 + r16) * PS + ks * 32 + quad * 8];
#pragma unroll
    for (int ni = 0; ni < 4; ++ni)
#pragma unroll
        for (int ks = 0; ks < 4; ++ks) {
            const bf16x8 bv = *(const bf16x8*)&Vs[(ni * 16 + r16) * VS + ks * 32 + quad * 8];
#pragma unroll
            for (int mi = 0; mi < 2; ++mi)
                O[mi][ni] = __builtin_amdgcn_mfma_f32_16x16x32_bf16(ap[mi][ks], bv, O[mi][ni], 0, 0, 0);
        }

    unsigned short* ob = msgT + (b * 4096 + n0) * 1024 + h * 64;
#pragma unroll
    for (int mi = 0; mi < 2; ++mi)
#pragma unroll
        for (int ni = 0; ni < 4; ++ni)
#pragma unroll
            for (int r = 0; r < 4; ++r)
                ob[(size_t)(w * 32 + mi * 16 + quad * 4 + r) * 1024 + ni * 16 + r16] =
                    f2bf(O[mi][ni][r] * linv[mi][r]);
}

// ---------------------------------------------------------------------------
extern "C" void kernel_launch(void* const* d_in, const int* in_sizes, int n_in,
                              void* d_out, int out_size, void* d_ws, size_t ws_size,
                              hipStream_t stream)
{
    (void)in_sizes; (void)n_in; (void)out_size; (void)ws_size;
    const float* x    = (const float*)d_in[0];
    const float* srcp = (const float*)d_in[1];
    const float* Wq   = (const float*)d_in[2];
    const float* bq   = (const float*)d_in[3];
    const float* Wk   = (const float*)d_in[4];
    const float* bk   = (const float*)d_in[5];
    const float* proj = (const float*)d_in[6];
    const float* Wm   = (const float*)d_in[7];
    const float* bm   = (const float*)d_in[8];
    const float* W1   = (const float*)d_in[9];
    const float* b1   = (const float*)d_in[10];
    const float* gam  = (const float*)d_in[11];
    const float* bet  = (const float*)d_in[12];
    const float* mu   = (const float*)d_in[13];
    const float* var  = (const float*)d_in[14];
    const float* W2   = (const float*)d_in[15];
    const float* b2   = (const float*)d_in[16];
    float* out = (float*)d_out;
    unsigned short* ws = (unsigned short*)d_ws;

    const long long E = 16777216LL;  // 4*4096*1024
    unsigned short* xt  = ws;
    unsigned short* st  = xt + E;
    unsigned short* qt  = st + E;
    unsigned short* kc  = qt + E;
    unsigned short* ht  = kc + E;
    unsigned short* pT  = ht + 2 * E;
    unsigned short* kpb = pT + 524288;
    unsigned short* wqb = kpb + 524288;
    unsigned short* wkb = wqb + 1048576;
    unsigned short* wmb = wkb + 1048576;
    unsigned short* w1b = wmb + 1048576;
    unsigned short* w2b = w1b + 4194304;
    float* bqp = (float*)(w2b + 2097152);
    float* bkp = bqp + 1024;
    float* kpacc = (float*)ht;  // kp split-K partials alias ht (not yet live)

    cvt_transpose_xs<<<dim3(128, 32, 8), 256, 0, stream>>>(x, srcp, xt, st);
    cvt_transpose<<<dim3(4, 128, 1), 256, 0, stream>>>(proj, pT, 4096, 128);
    prep_weights<<<9220, 256, 0, stream>>>(Wq, Wk, Wm, W1, W2, bq, bk,
                                           wqb, wkb, wmb, w1b, w2b, bqp, bkp);

    gemm_bt<1024, 1024, 1024, 1024, 1, false><<<dim3(8, 32, 4), 256, 0, stream>>>(
        xt, nullptr, 1024, wqb, qt, nullptr,
        4096LL * 1024, 0LL, 4096LL * 1024, nullptr, bqp,
        nullptr, nullptr, nullptr, nullptr);
    gemm_bt<1024, 1024, 4096, 1024, 1, false><<<dim3(32, 8, 4), 256, 0, stream>>>(
        wkb, nullptr, 1024, st, kc, nullptr,
        0LL, 4096LL * 1024, 1024LL * 4096, bkp, nullptr,
        nullptr, nullptr, nullptr, nullptr);
    gemm_bt<4096, 4096, 128, 4096, 8, false><<<dim3(1, 8, 32), 256, 0, stream>>>(
        kc, nullptr, 4096, pT, nullptr, kpacc,
        1024LL * 4096, 0LL, 1024LL * 128, nullptr, nullptr,
        nullptr, nullptr, nullptr, nullptr);
    reduce_kp<<<512, 256, 0, stream>>>(kpacc, kpb);
    attn_fused<<<dim3(32, 16, 4), 256, 0, stream>>>(qt, kpb, qt);
    gemm_bt<1024, 1024, 1024, 1024, 1, false><<<dim3(8, 32, 4), 256, 0, stream>>>(
        qt, nullptr, 1024, wmb, st, nullptr,
        4096LL * 1024, 0LL, 4096LL * 1024, nullptr, bm,
        nullptr, nullptr, nullptr, nullptr);
    gemm_bt<1024, 2048, 2048, 2048, 1, true><<<dim3(16, 32, 4), 256, 0, stream>>>(
        xt, st, 1024, w1b, ht, nullptr,
        4096LL * 1024, 0LL, 4096LL * 2048, nullptr, b1,
        gam, bet, mu, var);
    gemm_bt<2048, 2048, 4096, 2048, 1, false><<<dim3(32, 8, 4), 256, 0, stream>>>(
        w2b, nullptr, 2048, ht, nullptr, out,
        0LL, 4096LL * 2048, 1024LL * 4096, b2, nullptr,
        nullptr, nullptr, nullptr, nullptr);
}